// Round 1
// baseline (6944.520 us; speedup 1.0000x reference)
//
#include <hip/hip_runtime.h>
#include <hip/hip_bf16.h>

typedef __bf16 bf16;
typedef __bf16 bf16x8 __attribute__((ext_vector_type(8)));
typedef __bf16 bf16x4 __attribute__((ext_vector_type(4)));
typedef float f32x4 __attribute__((ext_vector_type(4)));

#define NB 16
#define NT 128
#define ND 512
#define NH 512
#define NC 4096
#define NG 16384  // 4*NC

// ws element-offset plan (bytes)
#define OFF_WI 0UL                       // 4 * 16384*512 * 2B = 67108864
#define OFF_WS 67108864UL                // + 67108864
#define OFF_WP 134217728UL               // 4 * 512*4096 * 2B = 16777216
#define OFF_A0 150994944UL               // 2048*512*2B = 2097152
#define OFF_A1F 153092096UL
#define OFF_A1B 155189248UL
#define OFF_XP 157286400UL               // 2 * 128*16*16384 * 2B = 134217728
#define OFF_H  291504128UL               // 2*16*512*2B = 32768
#define OFF_C  291536896UL               // 2*16*4096*4B = 524288
#define OFF_AB 292061184UL               // 2*16*4096*2B = 262144
#define WS_NEED 292323328UL

#define WI_SLAB (16384UL*512UL)
#define WP_SLAB (512UL*4096UL)
#define XP_SLAB (128UL*16UL*16384UL)

__device__ __forceinline__ float sigm_(float x){ return 1.f/(1.f + __expf(-x)); }
__device__ __forceinline__ float tanh_(float x){ return 1.f - 2.f/(__expf(2.f*x) + 1.f); }

// ---------- generic f32 -> bf16 cast (layout preserved) ----------
__global__ __launch_bounds__(256) void k_cast(const float* __restrict__ src,
                                              bf16* __restrict__ dst, int n4){
  int i = blockIdx.x*blockDim.x + threadIdx.x;
  int stride = gridDim.x*blockDim.x;
  const float4* s4 = (const float4*)src;
  bf16x4* d4 = (bf16x4*)dst;
  for (; i < n4; i += stride){
    float4 v = s4[i];
    bf16x4 o = {(bf16)v.x, (bf16)v.y, (bf16)v.z, (bf16)v.w};
    d4[i] = o;
  }
}

// ---------- x (B,T,512) f32 -> A0 (t,b,512) bf16 ----------
__global__ __launch_bounds__(256) void k_castx(const float* __restrict__ x,
                                               bf16* __restrict__ dst){
  int g = blockIdx.x*256 + threadIdx.x;       // 0 .. 262143
  int d = (g & 127) * 4;
  int r = g >> 7;                              // b*128 + t
  int b = r >> 7, t = r & 127;
  float4 v = ((const float4*)x)[g];
  bf16x4 o = {(bf16)v.x, (bf16)v.y, (bf16)v.z, (bf16)v.w};
  *(bf16x4*)(dst + (size_t)(t*16 + b)*512 + d) = o;
}

// ---------- layer-0 output (B,T,1024) f32 -> A1f/A1b (t,b,512) bf16 ----------
__global__ __launch_bounds__(256) void k_castout(const float* __restrict__ out0,
                                                 bf16* __restrict__ a1f,
                                                 bf16* __restrict__ a1b){
  int g = blockIdx.x*256 + threadIdx.x;       // 0 .. 524287
  int hh = (g & 255) * 4;
  int r = g >> 8;                              // b*128 + t
  int b = r >> 7, t = r & 127;
  float4 v = ((const float4*)out0)[g];
  bf16x4 o = {(bf16)v.x, (bf16)v.y, (bf16)v.z, (bf16)v.w};
  if (hh < 512) *(bf16x4*)(a1f + (size_t)(t*16 + b)*512 + hh) = o;
  else          *(bf16x4*)(a1b + (size_t)(t*16 + b)*512 + hh - 512) = o;
}

// ---------- input GEMM: Xp[m][n] = sum_k A[m][k]*W[n][k] + bias[n]  (M=2048,N=16384,K=512)
__global__ __launch_bounds__(256) void k_gemm_in(const bf16* __restrict__ A,
                                                 const bf16* __restrict__ W,
                                                 const float* __restrict__ bias,
                                                 bf16* __restrict__ Xp){
  int lane = threadIdx.x & 63, w = threadIdx.x >> 6;
  int n0 = blockIdx.x*256 + w*64;
  int m0 = blockIdx.y*64;
  int lm = lane & 15, lq = lane >> 4;
  f32x4 acc[4][4] = {};
  for (int kk = 0; kk < 512; kk += 32){
    int kc = kk + lq*8;
    bf16x8 af[4];
#pragma unroll
    for (int mt = 0; mt < 4; mt++)
      af[mt] = *(const bf16x8*)(A + (size_t)(m0 + mt*16 + lm)*512 + kc);
#pragma unroll
    for (int nt = 0; nt < 4; nt++){
      bf16x8 bfr = *(const bf16x8*)(W + (size_t)(n0 + nt*16 + lm)*512 + kc);
#pragma unroll
      for (int mt = 0; mt < 4; mt++)
        acc[mt][nt] = __builtin_amdgcn_mfma_f32_16x16x32_bf16(af[mt], bfr, acc[mt][nt], 0, 0, 0);
    }
  }
#pragma unroll
  for (int mt = 0; mt < 4; mt++)
#pragma unroll
    for (int nt = 0; nt < 4; nt++)
#pragma unroll
      for (int r = 0; r < 4; r++){
        int row = m0 + mt*16 + lq*4 + r;
        int col = n0 + nt*16 + lm;
        Xp[(size_t)row*16384 + col] = (bf16)(acc[mt][nt][r] + bias[col]);
      }
}

// ---------- per-step gates + cell update (both dirs in grid) ----------
__global__ __launch_bounds__(256) void k_gates(const bf16* __restrict__ Wsb,
                                               const bf16* __restrict__ Xp,
                                               const bf16* __restrict__ hbuf,
                                               float* __restrict__ cbuf,
                                               bf16* __restrict__ abuf,
                                               const int* __restrict__ len,
                                               int l, int s){
  int lane = threadIdx.x & 63, w = threadIdx.x >> 6;
  int dir = blockIdx.x >> 6;
  int c0 = (blockIdx.x & 63)*64 + w*16;
  int lm = lane & 15, lq = lane >> 4;
  const bf16* Wsd = Wsb + (size_t)(l*2 + dir)*WI_SLAB;
  const bf16* hd  = hbuf + (size_t)(dir*16)*512;
  f32x4 acc[4] = {};
  for (int kk = 0; kk < 512; kk += 32){
    int kc = kk + lq*8;
    bf16x8 af = *(const bf16x8*)(hd + (size_t)lm*512 + kc);
#pragma unroll
    for (int g = 0; g < 4; g++){
      bf16x8 bfr = *(const bf16x8*)(Wsd + (size_t)(g*4096 + c0 + lm)*512 + kc);
      acc[g] = __builtin_amdgcn_mfma_f32_16x16x32_bf16(af, bfr, acc[g], 0, 0, 0);
    }
  }
  const bf16* Xpd = Xp + (size_t)dir*XP_SLAB;
  int c_idx = c0 + lm;
#pragma unroll
  for (int r = 0; r < 4; r++){
    int b = lq*4 + r;
    int L = len[b];
    bool valid = (s < L);
    int u = dir ? (L - 1 - s) : s;
    u = u < 0 ? 0 : (u > 127 ? 127 : u);
    float pre[4];
#pragma unroll
    for (int g = 0; g < 4; g++)
      pre[g] = acc[g][r] + (float)Xpd[(size_t)(u*16 + b)*16384 + g*4096 + c_idx];
    float ig = sigm_(pre[0]);
    float fg = sigm_(pre[1]);
    float gg = tanh_(pre[2]);
    float og = sigm_(pre[3]);
    int cix = (dir*16 + b)*4096 + c_idx;
    float cold = cbuf[cix];
    float cnew = fminf(fmaxf(ig*gg + fg*cold, -3.f), 3.f);
    float av = og * tanh_(cnew);
    abuf[cix] = (bf16)av;
    if (valid) cbuf[cix] = cnew;
  }
}

// ---------- per-step projection h = clip(a @ Wp.T), output write (+residual l=1) ----------
__global__ __launch_bounds__(256) void k_proj(const bf16* __restrict__ Wpb,
                                              const bf16* __restrict__ abuf,
                                              bf16* __restrict__ hbuf,
                                              float* __restrict__ out,
                                              const int* __restrict__ len,
                                              int l, int s){
  __shared__ float red[4*64*4];
  int lane = threadIdx.x & 63, w = threadIdx.x >> 6;
  int dir = blockIdx.x >> 5;
  int h0 = (blockIdx.x & 31)*16;
  int lm = lane & 15, lq = lane >> 4;
  const bf16* Wpd = Wpb + (size_t)(l*2 + dir)*WP_SLAB;
  const bf16* ad  = abuf + (size_t)(dir*16)*4096;
  f32x4 acc = {};
  for (int kk = w*1024; kk < w*1024 + 1024; kk += 32){
    int kc = kk + lq*8;
    bf16x8 af  = *(const bf16x8*)(ad + (size_t)lm*4096 + kc);
    bf16x8 bfr = *(const bf16x8*)(Wpd + (size_t)(h0 + lm)*4096 + kc);
    acc = __builtin_amdgcn_mfma_f32_16x16x32_bf16(af, bfr, acc, 0, 0, 0);
  }
#pragma unroll
  for (int r = 0; r < 4; r++) red[(w*64 + lane)*4 + r] = acc[r];
  __syncthreads();
  if (w == 0){
#pragma unroll
    for (int r = 0; r < 4; r++){
      float pre = red[(lane)*4 + r] + red[(64 + lane)*4 + r] +
                  red[(128 + lane)*4 + r] + red[(192 + lane)*4 + r];
      int b = lq*4 + r;
      int L = len[b];
      if (s < L){
        float hn = fminf(fmaxf(pre, -3.f), 3.f);
        int hh = h0 + lm;
        hbuf[(size_t)(dir*16 + b)*512 + hh] = (bf16)hn;
        int u = dir ? (L - 1 - s) : s;
        size_t oidx = ((size_t)(l*16 + b)*128 + u)*1024 + dir*512 + hh;
        float val = hn;
        if (l == 1) val += out[((size_t)b*128 + u)*1024 + dir*512 + hh];
        out[oidx] = val;
      }
    }
  }
}

extern "C" void kernel_launch(void* const* d_in, const int* in_sizes, int n_in,
                              void* d_out, int out_size, void* d_ws, size_t ws_size,
                              hipStream_t stream) {
  const float* x   = (const float*)d_in[0];
  const int*   sl  = (const int*)d_in[1];
  const float* Wi  = (const float*)d_in[2];
  const float* Ws  = (const float*)d_in[3];
  const float* bia = (const float*)d_in[4];
  const float* Wp  = (const float*)d_in[5];
  float* out = (float*)d_out;
  char* ws = (char*)d_ws;

  bf16* WiB = (bf16*)(ws + OFF_WI);
  bf16* WsB = (bf16*)(ws + OFF_WS);
  bf16* WpB = (bf16*)(ws + OFF_WP);
  bf16* A0  = (bf16*)(ws + OFF_A0);
  bf16* A1F = (bf16*)(ws + OFF_A1F);
  bf16* A1B = (bf16*)(ws + OFF_A1B);
  bf16* XpB = (bf16*)(ws + OFF_XP);
  bf16* Hb  = (bf16*)(ws + OFF_H);
  float* Cb = (float*)(ws + OFF_C);
  bf16* Ab  = (bf16*)(ws + OFF_AB);

  // weight casts (stateless: redone every call)
  k_cast<<<2048, 256, 0, stream>>>(Wi, WiB, 8388608);
  k_cast<<<2048, 256, 0, stream>>>(Ws, WsB, 8388608);
  k_cast<<<2048, 256, 0, stream>>>(Wp, WpB, 2097152);

  // zero output + initial state
  hipMemsetAsync(d_out, 0, (size_t)out_size*4, stream);
  hipMemsetAsync(Hb, 0, 32768, stream);
  hipMemsetAsync(Cb, 0, 524288, stream);

  for (int l = 0; l < 2; ++l){
    if (l == 0){
      k_castx<<<1024, 256, 0, stream>>>(x, A0);
      k_gemm_in<<<dim3(64,32), 256, 0, stream>>>(A0, WiB,              bia,          XpB);
      k_gemm_in<<<dim3(64,32), 256, 0, stream>>>(A0, WiB + WI_SLAB,    bia + 16384,  XpB + XP_SLAB);
    } else {
      k_castout<<<2048, 256, 0, stream>>>(out, A1F, A1B);
      k_gemm_in<<<dim3(64,32), 256, 0, stream>>>(A1F, WiB + 2*WI_SLAB, bia + 2*16384, XpB);
      k_gemm_in<<<dim3(64,32), 256, 0, stream>>>(A1B, WiB + 3*WI_SLAB, bia + 3*16384, XpB + XP_SLAB);
      hipMemsetAsync(Hb, 0, 32768, stream);
      hipMemsetAsync(Cb, 0, 524288, stream);
    }
    for (int s = 0; s < 128; ++s){
      k_gates<<<128, 256, 0, stream>>>(WsB, XpB, Hb, Cb, Ab, sl, l, s);
      k_proj<<<64, 256, 0, stream>>>(WpB, Ab, Hb, out, sl, l, s);
    }
  }
}